// Round 3
// baseline (223.554 us; speedup 1.0000x reference)
//
#include <hip/hip_runtime.h>

#define B_ 16
#define N_ 4096
#define F_ 8
#define H_ 64
#define C_ 256
#define FH 512      // F_*H_
#define CAP 256     // max nodes per segment (binomial mean 16, sd 4; 256 unreachable)

// ---------------------------------------------------------------------------
// R3: two-kernel design.
//
// Evidence so far: three structurally different pooling schedules (R0/R1/R2)
// all land at kernel ~45-50us vs ~23us HBM floor. Phase-2 scheduling is NOT
// the lever. R3 removes the two remaining suspects common to all rounds:
//   (a) __launch_bounds__(256,6) capped VGPR at 85 < live state (~100) ->
//       likely scratch spills inside the hot loop (hidden HBM traffic).
//       Now (256,4): cap 128, no spill, still 4 blocks/CU.
//   (b) per-block seg scan (4096 x 16KB L2 + serialized LDS atomics on one
//       address + prologue barrier). Now done ONCE per c by a tiny ballot-
//       compaction kernel (no atomics), lists stored in workspace in
//       ASCENDING node order (DRAM page locality bonus for the gather).
// If dur_us stays ~200 after this, the scattered 2KB-row gather itself is
// the memory-system ceiling for this op -> declare roofline.
// ---------------------------------------------------------------------------

// Kernel 1: ordered per-segment node lists via wave ballot compaction.
// Grid = C_ blocks x 64 threads (1 wave). Block c scans seg[] in index
// order; ballot+popc compaction appends matches -> lists sorted ascending.
__global__ __launch_bounds__(64) void build_lists_kernel(
    const int* __restrict__ seg, int* __restrict__ lists, int* __restrict__ cnts)
{
    int c    = blockIdx.x;
    int lane = threadIdx.x;          // 0..63
    int* listc = lists + c * CAP;
    int base = 0;
#pragma unroll 4
    for (int k = 0; k < N_ / 64; k++) {
        int i = k * 64 + lane;
        bool pred = (seg[i] == c);
        unsigned long long mask = __ballot(pred);
        int idx = __popcll(mask & ((1ull << lane) - 1ull));
        if (pred && (base + idx) < CAP) listc[base + idx] = i;
        base += __popcll(mask);
    }
    if (lane == 0) cnts[c] = (base < CAP) ? base : CAP;
}

// Kernel 2: pooling. One block of 256 threads (4 waves) per (b, c).
// Wave w covers rows {w*4..w*4+3} mod 16 round-robin; one row per 32-lane
// group (lane pos covers elements 4*pos + 128k, k=0..3; W quad identical
// for all k). All 8 wave-loads issued before any use. 5-step shfl reduce
// serves both groups' rows; one exp per 2 rows. Cross-group xor-32 shfl,
// then cross-wave LDS combine (single barrier), normalize, store.
__device__ __forceinline__ float dot4(const float4 a, const float4 w) {
    return (a.x * w.x + a.y * w.y) + (a.z * w.z + a.w * w.w);
}

__global__ __launch_bounds__(256, 4) void pool_kernel(
    const float* __restrict__ x, const float* __restrict__ W,
    const float* __restrict__ bias, const int* __restrict__ lists,
    const int* __restrict__ cnts, float* __restrict__ out)
{
    int c    = blockIdx.x & (C_ - 1);
    int b    = blockIdx.x >> 8;       // batch 0..15
    int t    = threadIdx.x;           // 0..255
    int wave = t >> 6;                // 0..3
    int lane = t & 63;
    int grp  = lane >> 5;             // 0..1 (32-lane row group)
    int pos  = lane & 31;

    __shared__ float4 acc_sh[4][4][32];   // [wave][k][pos] - lane-consecutive
    __shared__ float  es_sh[4];

    int m = cnts[c];                   // L2-hot, wave-uniform -> broadcast
    const int* listc = lists + c * CAP;

    float4 w4 = *(const float4*)(W + ((4 * pos) & (H_ - 1)));
    float  bb = bias[0];
    const float4* x4 = (const float4*)x;
    size_t batch_base = (size_t)b * (N_ * (FH / 4));

    float4 acc0 = {0,0,0,0}, acc1 = {0,0,0,0}, acc2 = {0,0,0,0}, acc3 = {0,0,0,0};
    float  esum = 0.0f;

    for (int base = wave * 4; base < m; base += 16) {
        int r0 = base + grp;          // rows base, base+1
        int r1 = base + 2 + grp;      // rows base+2, base+3
        int a0 = (r0 < m), a1 = (r1 < m);
        int n0 = listc[a0 ? r0 : 0];  // L2-hot broadcast loads (64B/block)
        int n1 = listc[a1 ? r1 : 0];
        const float4* p0 = x4 + (batch_base + ((size_t)n0 << 7) + pos);
        const float4* p1 = x4 + (batch_base + ((size_t)n1 << 7) + pos);

        float4 v00, v01, v02, v03, v10, v11, v12, v13;
        if (a0) { v00 = p0[0]; v01 = p0[32]; v02 = p0[64]; v03 = p0[96]; }
        else    { v00 = v01 = v02 = v03 = make_float4(0.f, 0.f, 0.f, 0.f); }
        if (a1) { v10 = p1[0]; v11 = p1[32]; v12 = p1[64]; v13 = p1[96]; }
        else    { v10 = v11 = v12 = v13 = make_float4(0.f, 0.f, 0.f, 0.f); }

        float d0 = (dot4(v00, w4) + dot4(v01, w4)) + (dot4(v02, w4) + dot4(v03, w4));
        float d1 = (dot4(v10, w4) + dot4(v11, w4)) + (dot4(v12, w4) + dot4(v13, w4));
#pragma unroll
        for (int off = 16; off > 0; off >>= 1) {
            d0 += __shfl_xor(d0, off);
            d1 += __shfl_xor(d1, off);
        }
        float e0 = a0 ? __expf(d0 * (1.0f / F_) + bb) : 0.0f;
        float e1 = a1 ? __expf(d1 * (1.0f / F_) + bb) : 0.0f;
        esum += e0 + e1;
        acc0.x += e0 * v00.x + e1 * v10.x; acc0.y += e0 * v00.y + e1 * v10.y;
        acc0.z += e0 * v00.z + e1 * v10.z; acc0.w += e0 * v00.w + e1 * v10.w;
        acc1.x += e0 * v01.x + e1 * v11.x; acc1.y += e0 * v01.y + e1 * v11.y;
        acc1.z += e0 * v01.z + e1 * v11.z; acc1.w += e0 * v01.w + e1 * v11.w;
        acc2.x += e0 * v02.x + e1 * v12.x; acc2.y += e0 * v02.y + e1 * v12.y;
        acc2.z += e0 * v02.z + e1 * v12.z; acc2.w += e0 * v02.w + e1 * v12.w;
        acc3.x += e0 * v03.x + e1 * v13.x; acc3.y += e0 * v03.y + e1 * v13.y;
        acc3.z += e0 * v03.z + e1 * v13.z; acc3.w += e0 * v03.w + e1 * v13.w;
    }

    // ---- cross-group combine: grp0 + grp1 via xor-32 shfl adds ----
    acc0.x += __shfl_xor(acc0.x, 32); acc0.y += __shfl_xor(acc0.y, 32);
    acc0.z += __shfl_xor(acc0.z, 32); acc0.w += __shfl_xor(acc0.w, 32);
    acc1.x += __shfl_xor(acc1.x, 32); acc1.y += __shfl_xor(acc1.y, 32);
    acc1.z += __shfl_xor(acc1.z, 32); acc1.w += __shfl_xor(acc1.w, 32);
    acc2.x += __shfl_xor(acc2.x, 32); acc2.y += __shfl_xor(acc2.y, 32);
    acc2.z += __shfl_xor(acc2.z, 32); acc2.w += __shfl_xor(acc2.w, 32);
    acc3.x += __shfl_xor(acc3.x, 32); acc3.y += __shfl_xor(acc3.y, 32);
    acc3.z += __shfl_xor(acc3.z, 32); acc3.w += __shfl_xor(acc3.w, 32);
    esum  += __shfl_xor(esum, 32);

    if (lane < 32) {
        acc_sh[wave][0][pos] = acc0;
        acc_sh[wave][1][pos] = acc1;
        acc_sh[wave][2][pos] = acc2;
        acc_sh[wave][3][pos] = acc3;
        if (lane == 0) es_sh[wave] = esum;
    }
    __syncthreads();

    // ---- cross-wave combine, normalize, store ----
    if (t < 128) {
        int kk = t >> 5, pp = t & 31;     // out float4 idx = pp + 32*kk == t
        float es  = es_sh[0] + es_sh[1] + es_sh[2] + es_sh[3];
        float inv = (m > 0) ? 1.0f / es : 0.0f;   // empty segment -> zeros
        float4 s0 = acc_sh[0][kk][pp];
        float4 s1 = acc_sh[1][kk][pp];
        float4 s2 = acc_sh[2][kk][pp];
        float4 s3 = acc_sh[3][kk][pp];
        float4 r;
        r.x = (s0.x + s1.x + s2.x + s3.x) * inv;
        r.y = (s0.y + s1.y + s2.y + s3.y) * inv;
        r.z = (s0.z + s1.z + s2.z + s3.z) * inv;
        r.w = (s0.w + s1.w + s2.w + s3.w) * inv;
        size_t ob = ((size_t)(b * C_ + c)) * (FH / 4);
        ((float4*)out)[ob + t] = r;
    }
}

// ---------------------------------------------------------------------------
extern "C" void kernel_launch(void* const* d_in, const int* in_sizes, int n_in,
                              void* d_out, int out_size, void* d_ws, size_t ws_size,
                              hipStream_t stream)
{
    const float* x    = (const float*)d_in[0];
    const float* W    = (const float*)d_in[1];
    const float* bias = (const float*)d_in[2];
    const int*   seg  = (const int*)d_in[3];
    float* out = (float*)d_out;

    int* lists = (int*)d_ws;                 // C_*CAP ints = 256 KB
    int* cnts  = lists + C_ * CAP;           // C_ ints

    build_lists_kernel<<<C_, 64, 0, stream>>>(seg, lists, cnts);
    pool_kernel<<<B_ * C_, 256, 0, stream>>>(x, W, bias, lists, cnts, out);
}

// Round 4
// 202.052 us; speedup vs baseline: 1.1064x; 1.1064x over previous
//
#include <hip/hip_runtime.h>

#define B_ 16
#define N_ 4096
#define F_ 8
#define H_ 64
#define C_ 256
#define FH 512      // F_*H_
#define CAP 256     // max nodes per segment (binomial mean 16, sd 4; 256 unreachable)

// ---------------------------------------------------------------------------
// R4: single kernel, one block of 256 threads (4 waves) per (batch-pair, c).
// Grid = (B_/2) * C_ = 2048 blocks.
//
// Ledger so far: R0 (block per c x 4 batches) / R1 (block per (b,c), 6/CU) /
// R2 (burst-issue 8KB/wave) / R3 (scan-free sorted lists, spill-free) all
// give pool time ~45-50us vs 22.6us HBM floor. Scan, spills, occupancy and
// intra-task issue width are each falsified as the limiter.
//
// R4 tests the LAST untested axis: cross-task pipelining inside a wave.
//  * One ballot-compaction scan (wave-parallel 2-pass, sorted, NO atomics,
//    no extra kernel -> undoes R3's +21us serialization) serves 2 batches.
//  * Per wave-iteration: 4 rows x 2 batches = 16 KB of loads issued
//    back-to-back before ANY use; batch-0 compute runs while batch-1 loads
//    are still in flight (compiler vmcnt-counts). Live ~120 VGPR -> (256,4).
//  * Tail: ALL 256 threads store (t<128 -> batch 0, t>=128 -> batch 1);
//    scan+barrier+tail amortized over 2x traffic per block.
// If this is also null (kernel ~45us), the 2KB-granular random gather is at
// its delivered-BW ceiling (~3.2 TB/s) and dur_us is fill-dominated ->
// declare roofline.
// ---------------------------------------------------------------------------
__device__ __forceinline__ float dot4(const float4 a, const float4 w) {
    return (a.x * w.x + a.y * w.y) + (a.z * w.z + a.w * w.w);
}

__global__ __launch_bounds__(256, 4) void fused_pool_kernel(
    const float* __restrict__ x, const float* __restrict__ W,
    const float* __restrict__ bias, const int* __restrict__ seg,
    float* __restrict__ out)
{
    int c    = blockIdx.x & (C_ - 1);
    int bp   = blockIdx.x >> 8;       // batch pair 0..7 -> batches 2bp, 2bp+1
    int t    = threadIdx.x;           // 0..255
    int wave = t >> 6;                // 0..3
    int lane = t & 63;
    int grp  = lane >> 5;             // 0..1 (32-lane row group)
    int pos  = lane & 31;

    __shared__ int    list[CAP];
    __shared__ int    wcnt[4];
    __shared__ float4 acc_sh[2][4][4][32];   // [batch][wave][k][pos], 16 KB
    __shared__ float  es_sh[2][4];

    // ---- ballot-compaction scan: wave w covers nodes [w*1024, w*1024+1024) ----
    // pass 1: per-wave match count (uniform across lanes)
    int cl = 0;
#pragma unroll
    for (int k = 0; k < 16; k++) {
        int i = (wave * 16 + k) * 64 + lane;
        cl += (int)__popcll(__ballot(seg[i] == c));
    }
    if (lane == 0) wcnt[wave] = cl;
    __syncthreads();
    int base = 0, m = 0;
#pragma unroll
    for (int w2 = 0; w2 < 4; w2++) {
        int v = wcnt[w2];
        m += v;
        if (w2 < wave) base += v;
    }
    // pass 2: compacted, ascending-sorted writes
#pragma unroll
    for (int k = 0; k < 16; k++) {
        int i = (wave * 16 + k) * 64 + lane;
        bool pred = (seg[i] == c);
        unsigned long long mask = __ballot(pred);
        int idx = (int)__popcll(mask & ((1ull << lane) - 1ull));
        if (pred && (base + idx) < CAP) list[base + idx] = i;
        base += (int)__popcll(mask);
    }
    __syncthreads();
    if (m > CAP) m = CAP;

    // ---- main: 4 rows x 2 batches per wave-iteration, 16 KB in flight ----
    float4 w4 = *(const float4*)(W + ((4 * pos) & (H_ - 1)));
    float  bb = bias[0];
    const float4* x4 = (const float4*)x;
    size_t base0 = (size_t)(2 * bp)     * (N_ * (FH / 4));
    size_t base1 = (size_t)(2 * bp + 1) * (N_ * (FH / 4));

    float4 A0 = {0,0,0,0}, A1 = {0,0,0,0}, A2 = {0,0,0,0}, A3 = {0,0,0,0};
    float4 B0 = {0,0,0,0}, B1 = {0,0,0,0}, B2 = {0,0,0,0}, B3 = {0,0,0,0};
    float  es0 = 0.0f, es1 = 0.0f;

    for (int rb = wave * 4; rb < m; rb += 16) {
        int r0 = rb + grp;            // rows rb, rb+1 (one per 32-lane group)
        int r1 = rb + 2 + grp;        // rows rb+2, rb+3
        int a0 = (r0 < m), a1 = (r1 < m);
        int n0 = list[a0 ? r0 : 0];
        int n1 = list[a1 ? r1 : 0];
        size_t ro0 = ((size_t)n0 << 7) + pos;
        size_t ro1 = ((size_t)n1 << 7) + pos;
        const float4* p0 = x4 + base0 + ro0;   // batch 0, row r0
        const float4* p1 = x4 + base0 + ro1;   // batch 0, row r1
        const float4* q0 = x4 + base1 + ro0;   // batch 1, row r0
        const float4* q1 = x4 + base1 + ro1;   // batch 1, row r1

        float4 v00, v01, v02, v03, v10, v11, v12, v13;   // batch 0
        float4 u00, u01, u02, u03, u10, u11, u12, u13;   // batch 1
        if (a0) {
            v00 = p0[0]; v01 = p0[32]; v02 = p0[64]; v03 = p0[96];
            u00 = q0[0]; u01 = q0[32]; u02 = q0[64]; u03 = q0[96];
        } else {
            v00 = v01 = v02 = v03 = make_float4(0.f, 0.f, 0.f, 0.f);
            u00 = u01 = u02 = u03 = make_float4(0.f, 0.f, 0.f, 0.f);
        }
        if (a1) {
            v10 = p1[0]; v11 = p1[32]; v12 = p1[64]; v13 = p1[96];
            u10 = q1[0]; u11 = q1[32]; u12 = q1[64]; u13 = q1[96];
        } else {
            v10 = v11 = v12 = v13 = make_float4(0.f, 0.f, 0.f, 0.f);
            u10 = u11 = u12 = u13 = make_float4(0.f, 0.f, 0.f, 0.f);
        }

        // scores (4 independent shfl chains interleave -> ~1 chain latency)
        float d0 = (dot4(v00, w4) + dot4(v01, w4)) + (dot4(v02, w4) + dot4(v03, w4));
        float d1 = (dot4(v10, w4) + dot4(v11, w4)) + (dot4(v12, w4) + dot4(v13, w4));
        float g0 = (dot4(u00, w4) + dot4(u01, w4)) + (dot4(u02, w4) + dot4(u03, w4));
        float g1 = (dot4(u10, w4) + dot4(u11, w4)) + (dot4(u12, w4) + dot4(u13, w4));
#pragma unroll
        for (int off = 16; off > 0; off >>= 1) {
            d0 += __shfl_xor(d0, off);
            d1 += __shfl_xor(d1, off);
            g0 += __shfl_xor(g0, off);
            g1 += __shfl_xor(g1, off);
        }
        float e0 = a0 ? __expf(d0 * (1.0f / F_) + bb) : 0.0f;
        float e1 = a1 ? __expf(d1 * (1.0f / F_) + bb) : 0.0f;
        float f0 = a0 ? __expf(g0 * (1.0f / F_) + bb) : 0.0f;
        float f1 = a1 ? __expf(g1 * (1.0f / F_) + bb) : 0.0f;
        es0 += e0 + e1;
        es1 += f0 + f1;

        A0.x += e0 * v00.x + e1 * v10.x; A0.y += e0 * v00.y + e1 * v10.y;
        A0.z += e0 * v00.z + e1 * v10.z; A0.w += e0 * v00.w + e1 * v10.w;
        A1.x += e0 * v01.x + e1 * v11.x; A1.y += e0 * v01.y + e1 * v11.y;
        A1.z += e0 * v01.z + e1 * v11.z; A1.w += e0 * v01.w + e1 * v11.w;
        A2.x += e0 * v02.x + e1 * v12.x; A2.y += e0 * v02.y + e1 * v12.y;
        A2.z += e0 * v02.z + e1 * v12.z; A2.w += e0 * v02.w + e1 * v12.w;
        A3.x += e0 * v03.x + e1 * v13.x; A3.y += e0 * v03.y + e1 * v13.y;
        A3.z += e0 * v03.z + e1 * v13.z; A3.w += e0 * v03.w + e1 * v13.w;

        B0.x += f0 * u00.x + f1 * u10.x; B0.y += f0 * u00.y + f1 * u10.y;
        B0.z += f0 * u00.z + f1 * u10.z; B0.w += f0 * u00.w + f1 * u10.w;
        B1.x += f0 * u01.x + f1 * u11.x; B1.y += f0 * u01.y + f1 * u11.y;
        B1.z += f0 * u01.z + f1 * u11.z; B1.w += f0 * u01.w + f1 * u11.w;
        B2.x += f0 * u02.x + f1 * u12.x; B2.y += f0 * u02.y + f1 * u12.y;
        B2.z += f0 * u02.z + f1 * u12.z; B2.w += f0 * u02.w + f1 * u12.w;
        B3.x += f0 * u03.x + f1 * u13.x; B3.y += f0 * u03.y + f1 * u13.y;
        B3.z += f0 * u03.z + f1 * u13.z; B3.w += f0 * u03.w + f1 * u13.w;
    }

    // ---- cross-group combine (grp0 + grp1) for both batches ----
    A0.x += __shfl_xor(A0.x, 32); A0.y += __shfl_xor(A0.y, 32);
    A0.z += __shfl_xor(A0.z, 32); A0.w += __shfl_xor(A0.w, 32);
    A1.x += __shfl_xor(A1.x, 32); A1.y += __shfl_xor(A1.y, 32);
    A1.z += __shfl_xor(A1.z, 32); A1.w += __shfl_xor(A1.w, 32);
    A2.x += __shfl_xor(A2.x, 32); A2.y += __shfl_xor(A2.y, 32);
    A2.z += __shfl_xor(A2.z, 32); A2.w += __shfl_xor(A2.w, 32);
    A3.x += __shfl_xor(A3.x, 32); A3.y += __shfl_xor(A3.y, 32);
    A3.z += __shfl_xor(A3.z, 32); A3.w += __shfl_xor(A3.w, 32);
    B0.x += __shfl_xor(B0.x, 32); B0.y += __shfl_xor(B0.y, 32);
    B0.z += __shfl_xor(B0.z, 32); B0.w += __shfl_xor(B0.w, 32);
    B1.x += __shfl_xor(B1.x, 32); B1.y += __shfl_xor(B1.y, 32);
    B1.z += __shfl_xor(B1.z, 32); B1.w += __shfl_xor(B1.w, 32);
    B2.x += __shfl_xor(B2.x, 32); B2.y += __shfl_xor(B2.y, 32);
    B2.z += __shfl_xor(B2.z, 32); B2.w += __shfl_xor(B2.w, 32);
    B3.x += __shfl_xor(B3.x, 32); B3.y += __shfl_xor(B3.y, 32);
    B3.z += __shfl_xor(B3.z, 32); B3.w += __shfl_xor(B3.w, 32);
    es0  += __shfl_xor(es0, 32);
    es1  += __shfl_xor(es1, 32);

    if (lane < 32) {
        acc_sh[0][wave][0][pos] = A0;
        acc_sh[0][wave][1][pos] = A1;
        acc_sh[0][wave][2][pos] = A2;
        acc_sh[0][wave][3][pos] = A3;
        acc_sh[1][wave][0][pos] = B0;
        acc_sh[1][wave][1][pos] = B1;
        acc_sh[1][wave][2][pos] = B2;
        acc_sh[1][wave][3][pos] = B3;
        if (lane == 0) { es_sh[0][wave] = es0; es_sh[1][wave] = es1; }
    }
    __syncthreads();

    // ---- tail: all 256 threads; t<128 -> batch 0, t>=128 -> batch 1 ----
    {
        int bi = t >> 7;                  // 0 or 1
        int tb = t & 127;                 // out float4 idx within row
        int kk = tb >> 5, pp = tb & 31;
        float es  = es_sh[bi][0] + es_sh[bi][1] + es_sh[bi][2] + es_sh[bi][3];
        float inv = (m > 0) ? 1.0f / es : 0.0f;   // empty segment -> zeros
        float4 s0 = acc_sh[bi][0][kk][pp];
        float4 s1 = acc_sh[bi][1][kk][pp];
        float4 s2 = acc_sh[bi][2][kk][pp];
        float4 s3 = acc_sh[bi][3][kk][pp];
        float4 r;
        r.x = (s0.x + s1.x + s2.x + s3.x) * inv;
        r.y = (s0.y + s1.y + s2.y + s3.y) * inv;
        r.z = (s0.z + s1.z + s2.z + s3.z) * inv;
        r.w = (s0.w + s1.w + s2.w + s3.w) * inv;
        size_t ob = ((size_t)((2 * bp + bi) * C_ + c)) * (FH / 4);
        ((float4*)out)[ob + tb] = r;
    }
}

// ---------------------------------------------------------------------------
extern "C" void kernel_launch(void* const* d_in, const int* in_sizes, int n_in,
                              void* d_out, int out_size, void* d_ws, size_t ws_size,
                              hipStream_t stream)
{
    const float* x    = (const float*)d_in[0];
    const float* W    = (const float*)d_in[1];
    const float* bias = (const float*)d_in[2];
    const int*   seg  = (const int*)d_in[3];
    float* out = (float*)d_out;

    fused_pool_kernel<<<(B_ / 2) * C_, 256, 0, stream>>>(x, W, bias, seg, out);
}